// Round 2
// baseline (3274.989 us; speedup 1.0000x reference)
//
#include <hip/hip_runtime.h>
#include <math.h>

#define SB 32
#define SS 8192
#define SD 256
#define SH 512
#define CLIPV 3.0f

typedef __attribute__((ext_vector_type(8))) short bf16x8;
typedef __attribute__((ext_vector_type(4))) float f32x4;

__device__ __forceinline__ unsigned short f2bf(float f) {
    unsigned int u = __builtin_bit_cast(unsigned int, f);
    u = (u + 0x7FFFu + ((u >> 16) & 1u)) >> 16;   // RNE
    return (unsigned short)u;
}
__device__ __forceinline__ float bf2f(unsigned short h) {
    unsigned int u = ((unsigned int)h) << 16;
    return __builtin_bit_cast(float, u);
}

// ---------------------------------------------------------------------------
// k_prepw: split-transpose W1 (drive||resistance) into WT[col][k] bf16 hi/lo.
// col 0..511 = drive, 512..1023 = resistance.  1024 blocks x 256 threads.
// ---------------------------------------------------------------------------
__global__ __launch_bounds__(256) void k_prepw(
    const float* __restrict__ dw1, const float* __restrict__ rw1,
    unsigned short* __restrict__ WTh, unsigned short* __restrict__ WTl)
{
    const int c = blockIdx.x;
    const float* src = (c < SH) ? (dw1 + c) : (rw1 + (c - SH));
    const int k = threadIdx.x;                 // 0..255
    const float v = src[(size_t)k * SH];
    const unsigned short h = f2bf(v);
    const unsigned short l = f2bf(v - bf2f(h));
    WTh[(size_t)c * SD + k] = h;
    WTl[(size_t)c * SD + k] = l;
}

// ---------------------------------------------------------------------------
// k_logits: fused LayerNorm + split-bf16 MFMA dual-MLP -> logits.
// 64 rows/block, 4 waves as 2x2 over a 64x128 tile per n-iter.
// A (xhat hi/lo) in XOR-swizzled LDS; B (WT hi/lo) streamed from L2.
// C = Ah*Bh + Al*Bh + Ah*Bl  (fp32 accum; error ~1e-5 in logits).
// ---------------------------------------------------------------------------
__global__ __launch_bounds__(256, 2) void k_logits(
    const float* __restrict__ x,
    const float* __restrict__ gamma, const float* __restrict__ beta,
    const unsigned short* __restrict__ WTh, const unsigned short* __restrict__ WTl,
    const float* __restrict__ db1, const float* __restrict__ dw2, const float* __restrict__ db2,
    const float* __restrict__ rb1, const float* __restrict__ rw2, const float* __restrict__ rb2,
    float* __restrict__ logits, float* __restrict__ murstd)
{
    __shared__ unsigned short Ah[64 * SD];   // 32 KB, [row][k] ^ ((row&7)<<4) byte-swizzle
    __shared__ unsigned short Al[64 * SD];   // 32 KB
    __shared__ float sc[2][64][2];           // cross-wave partial sums (D,R)

    const int tid = threadIdx.x;
    const int l   = tid & 63;
    const int w   = tid >> 6;
    const size_t row0 = (size_t)blockIdx.x * 64;
    char* AhB = (char*)Ah;
    char* AlB = (char*)Al;

    // ---- stage: LayerNorm + hi/lo bf16 split into LDS -----------------------
    {
        const int r = (tid & 15) | ((tid >> 6) << 4);   // row 0..63
        const int q = (tid >> 4) & 3;                   // quarter of K
        const size_t row = row0 + (size_t)r;
        const float4* xr = (const float4*)(x + row * SD + q * 64);
        float4 v[16];
        float s = 0.f, sq = 0.f;
        #pragma unroll
        for (int i = 0; i < 16; ++i) {
            v[i] = xr[i];
            s  += v[i].x + v[i].y + v[i].z + v[i].w;
            sq += v[i].x*v[i].x + v[i].y*v[i].y + v[i].z*v[i].z + v[i].w*v[i].w;
        }
        s  += __shfl_xor(s, 16);  s  += __shfl_xor(s, 32);
        sq += __shfl_xor(sq, 16); sq += __shfl_xor(sq, 32);
        const float mu   = s * (1.0f / SD);
        const float var  = sq * (1.0f / SD) - mu * mu;
        const float rstd = rsqrtf(var + 1e-5f);
        if (q == 0) { murstd[2*row] = mu; murstd[2*row + 1] = rstd; }

        const float4* g4 = (const float4*)(gamma + q * 64);
        const float4* b4 = (const float4*)(beta  + q * 64);
        #pragma unroll
        for (int i = 0; i < 16; i += 2) {
            const float4 ga = g4[i], gb = g4[i+1];
            const float4 ba = b4[i], bb = b4[i+1];
            float xn[8];
            xn[0] = (v[i].x   - mu) * rstd * ga.x + ba.x;
            xn[1] = (v[i].y   - mu) * rstd * ga.y + ba.y;
            xn[2] = (v[i].z   - mu) * rstd * ga.z + ba.z;
            xn[3] = (v[i].w   - mu) * rstd * ga.w + ba.w;
            xn[4] = (v[i+1].x - mu) * rstd * gb.x + bb.x;
            xn[5] = (v[i+1].y - mu) * rstd * gb.y + bb.y;
            xn[6] = (v[i+1].z - mu) * rstd * gb.z + bb.z;
            xn[7] = (v[i+1].w - mu) * rstd * gb.w + bb.w;
            bf16x8 H, L;
            #pragma unroll
            for (int j = 0; j < 8; ++j) {
                const unsigned short hh = f2bf(xn[j]);
                H[j] = (short)hh;
                L[j] = (short)f2bf(xn[j] - bf2f(hh));
            }
            unsigned int off = (unsigned)(r * 512 + q * 128 + i * 8);
            off ^= (unsigned)((r & 7) << 4);
            *(bf16x8*)(AhB + off) = H;
            *(bf16x8*)(AlB + off) = L;
        }
    }
    __syncthreads();

    // ---- MFMA main: 2 phases (drive / resistance) x 4 n-iters of 128 cols ---
    const int wm = w >> 1, wn = w & 1;
    const int lr = l & 15, lk = l >> 4;
    const unsigned int aBase = (unsigned)((wm*32 + lr) * 512 + lk * 16);
    const unsigned int aSwz  = (unsigned)((lr & 7) << 4);

    float pd[8], pr[8];
    #pragma unroll
    for (int i = 0; i < 8; ++i) { pd[i] = 0.f; pr[i] = 0.f; }

    #pragma unroll
    for (int ph = 0; ph < 2; ++ph) {
        const float* B1 = ph ? rb1 : db1;
        const float* W2 = ph ? rw2 : dw2;
        #pragma unroll
        for (int n4 = 0; n4 < 4; ++n4) {
            const size_t colBase = (size_t)(ph * 512 + n4 * 128 + wn * 64);
            const unsigned short* bh0 = WTh + colBase * SD;
            const unsigned short* bl0 = WTl + colBase * SD;
            f32x4 acc[2][4];
            #pragma unroll
            for (int mi = 0; mi < 2; ++mi)
                #pragma unroll
                for (int ni = 0; ni < 4; ++ni)
                    acc[mi][ni] = (f32x4){0.f, 0.f, 0.f, 0.f};

            #pragma unroll
            for (int k = 0; k < 8; ++k) {
                bf16x8 bh[4], bl[4];
                #pragma unroll
                for (int ni = 0; ni < 4; ++ni) {
                    const unsigned short* p = bh0 + (size_t)(ni*16 + lr) * SD + k*32 + lk*8;
                    bh[ni] = *(const bf16x8*)p;
                    const unsigned short* p2 = bl0 + (size_t)(ni*16 + lr) * SD + k*32 + lk*8;
                    bl[ni] = *(const bf16x8*)p2;
                }
                bf16x8 ah[2], al[2];
                #pragma unroll
                for (int mi = 0; mi < 2; ++mi) {
                    const unsigned int off = (aBase + (unsigned)(mi*8192 + k*64)) ^ aSwz;
                    ah[mi] = *(const bf16x8*)(AhB + off);
                    al[mi] = *(const bf16x8*)(AlB + off);
                }
                #pragma unroll
                for (int mi = 0; mi < 2; ++mi)
                    #pragma unroll
                    for (int ni = 0; ni < 4; ++ni) {
                        acc[mi][ni] = __builtin_amdgcn_mfma_f32_16x16x32_bf16(ah[mi], bh[ni], acc[mi][ni], 0, 0, 0);
                        acc[mi][ni] = __builtin_amdgcn_mfma_f32_16x16x32_bf16(al[mi], bh[ni], acc[mi][ni], 0, 0, 0);
                        acc[mi][ni] = __builtin_amdgcn_mfma_f32_16x16x32_bf16(ah[mi], bl[ni], acc[mi][ni], 0, 0, 0);
                    }
            }
            // epilogue: bias + exact GELU + dot(w2), accumulate per-row partials
            #pragma unroll
            for (int ni = 0; ni < 4; ++ni) {
                const int col = n4*128 + wn*64 + ni*16 + lr;   // 0..511 within phase
                const float b1v = B1[col];
                const float w2v = W2[col];
                #pragma unroll
                for (int mi = 0; mi < 2; ++mi)
                    #pragma unroll
                    for (int rg = 0; rg < 4; ++rg) {
                        const float h = acc[mi][ni][rg] + b1v;
                        const float g = 0.5f * h * (1.0f + erff(h * 0.70710678118654752f));
                        if (ph == 0) pd[mi*4+rg] = fmaf(g, w2v, pd[mi*4+rg]);
                        else         pr[mi*4+rg] = fmaf(g, w2v, pr[mi*4+rg]);
                    }
            }
        }
    }

    // ---- reduce across the 16 'lr' lanes (wave-local) -----------------------
    #pragma unroll
    for (int m = 1; m <= 8; m <<= 1) {
        #pragma unroll
        for (int i = 0; i < 8; ++i) {
            pd[i] += __shfl_xor(pd[i], m);
            pr[i] += __shfl_xor(pr[i], m);
        }
    }
    if (lr == 0) {
        #pragma unroll
        for (int i = 0; i < 8; ++i) {
            const int row = wm*32 + (i >> 2)*16 + lk*4 + (i & 3);
            sc[wn][row][0] = pd[i];
            sc[wn][row][1] = pr[i];
        }
    }
    __syncthreads();
    if (tid < 64) {
        const float D = sc[0][tid][0] + sc[1][tid][0] + db2[0];
        const float R = sc[0][tid][1] + sc[1][tid][1] + rb2[0];
        const float sp = fmaxf(R, 0.f) + log1pf(expf(-fabsf(R)));
        float s = D - sp;
        s = fminf(CLIPV, fmaxf(-CLIPV, s));
        logits[row0 + (size_t)tid] = s;
    }
}

// ---------------------------------------------------------------------------
// K2: per-batch masked softmax over S + stable top-3 (tie-break lowest index).
// ---------------------------------------------------------------------------
__global__ __launch_bounds__(256) void k_softmax_topk(
    const float* __restrict__ logits, const int* __restrict__ mask,
    float* __restrict__ weights, float* __restrict__ ti, float* __restrict__ tw,
    float* __restrict__ flags)
{
    const int b = blockIdx.x, tid = threadIdx.x;
    const float* lg = logits + (size_t)b * SS;
    const int*   mk = mask   + (size_t)b * SS;
    float*       wt = weights + (size_t)b * SS;
    __shared__ float rv[4];
    __shared__ int   ri[4];
    __shared__ int   sCh[3];

    float mx = -INFINITY;
    for (int s = tid; s < SS; s += 256) if (mk[s]) mx = fmaxf(mx, lg[s]);
    #pragma unroll
    for (int off = 32; off; off >>= 1) mx = fmaxf(mx, __shfl_xor(mx, off));
    if ((tid & 63) == 0) rv[tid >> 6] = mx;
    __syncthreads();
    mx = fmaxf(fmaxf(rv[0], rv[1]), fmaxf(rv[2], rv[3]));
    __syncthreads();

    float sm = 0.f;
    for (int s = tid; s < SS; s += 256) if (mk[s]) sm += expf(lg[s] - mx);
    #pragma unroll
    for (int off = 32; off; off >>= 1) sm += __shfl_xor(sm, off);
    if ((tid & 63) == 0) rv[tid >> 6] = sm;
    __syncthreads();
    const float Z = rv[0] + rv[1] + rv[2] + rv[3];
    __syncthreads();
    const bool  any = (Z > 0.f) && (mx > -INFINITY);
    const float inv = any ? 1.0f / Z : 0.f;

    for (int s = tid; s < SS; s += 256) {
        const float w = (mk[s] && any) ? expf(lg[s] - mx) * inv : 0.f;
        wt[s] = w;
    }
    if (tid == 0) flags[b] = any ? 1.f : 0.f;
    __syncthreads();

    for (int t = 0; t < 3; ++t) {
        float bv = -1.f; int bi = 0;
        for (int s = tid; s < SS; s += 256) {
            bool ex = false;
            for (int u = 0; u < t; ++u) ex = ex || (s == sCh[u]);
            if (ex) continue;
            const float w = wt[s];
            if (w > bv || (w == bv && s < bi)) { bv = w; bi = s; }
        }
        #pragma unroll
        for (int off = 32; off; off >>= 1) {
            const float ov = __shfl_xor(bv, off);
            const int   oi = __shfl_xor(bi, off);
            if (ov > bv || (ov == bv && oi < bi)) { bv = ov; bi = oi; }
        }
        if ((tid & 63) == 0) { rv[tid >> 6] = bv; ri[tid >> 6] = bi; }
        __syncthreads();
        if (tid == 0) {
            for (int w2 = 1; w2 < 4; ++w2)
                if (rv[w2] > rv[0] || (rv[w2] == rv[0] && ri[w2] < ri[0])) { rv[0] = rv[w2]; ri[0] = ri[w2]; }
            sCh[t] = ri[0];
            ti[b*3 + t] = (float)ri[0];
            tw[b*3 + t] = rv[0];
        }
        __syncthreads();
    }
}

// ---------------------------------------------------------------------------
// K3: partial weighted sums over S-chunks (linearity: rep = (sum w*xhat)@vw).
// ---------------------------------------------------------------------------
__global__ __launch_bounds__(256) void k_wsum(
    const float* __restrict__ x, const float* __restrict__ weights,
    const float* __restrict__ murstd,
    const float* __restrict__ gamma, const float* __restrict__ beta,
    float* __restrict__ partials)
{
    const int c = blockIdx.x;
    const int b = blockIdx.y;
    const int d = threadIdx.x;
    const float gg = gamma[d], bb = beta[d];
    float acc = 0.f;
    const size_t base = (size_t)b * SS + (size_t)c * 128;
    for (int s = 0; s < 128; ++s) {
        const size_t row = base + s;
        const float w = weights[row];
        if (w != 0.f) {
            const float mu = murstd[2*row], rs = murstd[2*row+1];
            const float xv = x[row * SD + d];
            acc = fmaf(w, (xv - mu) * rs * gg + bb, acc);
        }
    }
    partials[((size_t)b * 64 + c) * SD + d] = acc;
}

// ---------------------------------------------------------------------------
// K4: reduce partials, rep[b] = svec @ vw + vb * anyMask
// ---------------------------------------------------------------------------
__global__ __launch_bounds__(256) void k_final(
    const float* __restrict__ partials, const float* __restrict__ flags,
    const float* __restrict__ vw, const float* __restrict__ vb,
    float* __restrict__ rep)
{
    const int b = blockIdx.x;
    const int t = threadIdx.x;
    __shared__ float sv[SD];
    float a = 0.f;
    for (int c = 0; c < 64; ++c) a += partials[((size_t)b * 64 + c) * SD + t];
    sv[t] = a;
    __syncthreads();
    const float f = flags[b];
    float r = vb[t] * f;
    for (int dd = 0; dd < SD; ++dd) r = fmaf(sv[dd], vw[(size_t)dd * 256 + t], r);
    rep[(size_t)b * 256 + t] = r;
}

// ---------------------------------------------------------------------------
extern "C" void kernel_launch(void* const* d_in, const int* in_sizes, int n_in,
                              void* d_out, int out_size, void* d_ws, size_t ws_size,
                              hipStream_t stream)
{
    const float* x     = (const float*)d_in[0];
    const int*   mask  = (const int*)  d_in[1];
    const float* gamma = (const float*)d_in[2];
    const float* beta  = (const float*)d_in[3];
    const float* dw1   = (const float*)d_in[4];
    const float* db1   = (const float*)d_in[5];
    const float* dw2   = (const float*)d_in[6];
    const float* db2   = (const float*)d_in[7];
    const float* rw1   = (const float*)d_in[8];
    const float* rb1   = (const float*)d_in[9];
    const float* rw2   = (const float*)d_in[10];
    const float* rb2   = (const float*)d_in[11];
    const float* vw    = (const float*)d_in[12];
    const float* vb    = (const float*)d_in[13];

    float* out     = (float*)d_out;
    float* rep     = out;                       // 32*256
    float* weights = out + 8192;                // 32*8192
    float* ti      = out + 8192 + 262144;       // 32*3
    float* tw      = ti + 96;                   // 32*3
    float* logits  = tw + 96;                   // 32*8192

    float* ws       = (float*)d_ws;
    float* murstd   = ws;                       // 524288 floats (2 MB)
    float* partials = ws + 524288;              // 524288 floats (2 MB)
    float* flags    = ws + 1048576;             // 32 floats (+pad to 16B)
    unsigned short* WTh = (unsigned short*)(ws + 1048608);          // 512 KB
    unsigned short* WTl = WTh + 262144;                              // 512 KB

    hipLaunchKernelGGL(k_prepw, dim3(1024), dim3(256), 0, stream,
                       dw1, rw1, WTh, WTl);
    hipLaunchKernelGGL(k_logits, dim3(4096), dim3(256), 0, stream,
                       x, gamma, beta, WTh, WTl,
                       db1, dw2, db2, rb1, rw2, rb2,
                       logits, murstd);
    hipLaunchKernelGGL(k_softmax_topk, dim3(32), dim3(256), 0, stream,
                       logits, mask, weights, ti, tw, flags);
    hipLaunchKernelGGL(k_wsum, dim3(64, 32), dim3(256), 0, stream,
                       x, weights, murstd, gamma, beta, partials);
    hipLaunchKernelGGL(k_final, dim3(32), dim3(256), 0, stream,
                       partials, flags, vw, vb, rep);
}

// Round 5
// 2212.306 us; speedup vs baseline: 1.4804x; 1.4804x over previous
//
#include <hip/hip_runtime.h>
#include <math.h>

#define SB 32
#define SS 8192
#define SD 256
#define SH 512
#define CLIPV 3.0f

typedef __attribute__((ext_vector_type(8))) _Float16 f16x8;
typedef __attribute__((ext_vector_type(4))) float f32x4;

// fp16-pair split: x = hi + lo with residual ~2^-22 |x|  (fp16 RNE both)
__device__ __forceinline__ void split16(float v, _Float16& h, _Float16& l) {
    h = (_Float16)v;                 // RNE f32->f16
    l = (_Float16)(v - (float)h);    // v - (float)h is exact in fp32
}

// ---------------------------------------------------------------------------
// k_prepw: split-transpose W1 (drive||resistance) into WT[col][k] fp16 hi/lo.
// ---------------------------------------------------------------------------
__global__ __launch_bounds__(256) void k_prepw(
    const float* __restrict__ dw1, const float* __restrict__ rw1,
    _Float16* __restrict__ WTh, _Float16* __restrict__ WTl)
{
    const int c = blockIdx.x;
    const float* src = (c < SH) ? (dw1 + c) : (rw1 + (c - SH));
    const int k = threadIdx.x;                 // 0..255
    const float v = src[(size_t)k * SH];
    _Float16 h, l;
    split16(v, h, l);
    WTh[(size_t)c * SD + k] = h;
    WTl[(size_t)c * SD + k] = l;
}

// ---------------------------------------------------------------------------
// k_logits: fused LayerNorm + 3-term split-fp16 MFMA dual-MLP -> logits.
// Structure identical to R4 (indexing validated); dtype bf16 -> fp16.
// C = Ah*Bh + Al*Bh + Ah*Bl ; dropped Al*Bl ~ 2^-22 rel (negligible).
// ---------------------------------------------------------------------------
__global__ __launch_bounds__(256, 2) void k_logits(
    const float* __restrict__ x,
    const float* __restrict__ gamma, const float* __restrict__ beta,
    const _Float16* __restrict__ WTh, const _Float16* __restrict__ WTl,
    const float* __restrict__ db1, const float* __restrict__ dw2, const float* __restrict__ db2,
    const float* __restrict__ rb1, const float* __restrict__ rw2, const float* __restrict__ rb2,
    float* __restrict__ logits, float* __restrict__ murstd)
{
    __shared__ _Float16 Ah[64 * SD];   // 32 KB, [row][k] ^ ((row&7)<<4) byte-swizzle
    __shared__ _Float16 Al[64 * SD];   // 32 KB

    const int tid = threadIdx.x;
    const size_t row0 = (size_t)blockIdx.x * 64;
    char* AhB = (char*)Ah;
    char* AlB = (char*)Al;

    // ---- stage: LayerNorm + hi/lo fp16 split into LDS -----------------------
    {
        const int r = (tid & 15) | ((tid >> 6) << 4);   // row 0..63
        const int q = (tid >> 4) & 3;                   // quarter of K
        const size_t row = row0 + (size_t)r;
        const float4* xr = (const float4*)(x + row * SD + q * 64);
        float4 v[16];
        float s = 0.f, sq = 0.f;
        #pragma unroll
        for (int i = 0; i < 16; ++i) {
            v[i] = xr[i];
            s  += v[i].x + v[i].y + v[i].z + v[i].w;
            sq += v[i].x*v[i].x + v[i].y*v[i].y + v[i].z*v[i].z + v[i].w*v[i].w;
        }
        s  += __shfl_xor(s, 16);  s  += __shfl_xor(s, 32);
        sq += __shfl_xor(sq, 16); sq += __shfl_xor(sq, 32);
        const float mu   = s * (1.0f / SD);
        const float var  = sq * (1.0f / SD) - mu * mu;
        const float rstd = rsqrtf(var + 1e-5f);
        if (q == 0) { murstd[2*row] = mu; murstd[2*row + 1] = rstd; }

        const float4* g4 = (const float4*)(gamma + q * 64);
        const float4* b4 = (const float4*)(beta  + q * 64);
        #pragma unroll
        for (int i = 0; i < 16; i += 2) {
            const float4 ga = g4[i], gb = g4[i+1];
            const float4 ba = b4[i], bb = b4[i+1];
            float xn[8];
            xn[0] = (v[i].x   - mu) * rstd * ga.x + ba.x;
            xn[1] = (v[i].y   - mu) * rstd * ga.y + ba.y;
            xn[2] = (v[i].z   - mu) * rstd * ga.z + ba.z;
            xn[3] = (v[i].w   - mu) * rstd * ga.w + ba.w;
            xn[4] = (v[i+1].x - mu) * rstd * gb.x + bb.x;
            xn[5] = (v[i+1].y - mu) * rstd * gb.y + bb.y;
            xn[6] = (v[i+1].z - mu) * rstd * gb.z + bb.z;
            xn[7] = (v[i+1].w - mu) * rstd * gb.w + bb.w;
            f16x8 H, L;
            #pragma unroll
            for (int j = 0; j < 8; ++j) {
                _Float16 hh, ll;
                split16(xn[j], hh, ll);
                H[j] = hh;
                L[j] = ll;
            }
            unsigned int off = (unsigned)(r * 512 + q * 128 + i * 8);
            off ^= (unsigned)((r & 7) << 4);
            *(f16x8*)(AhB + off) = H;
            *(f16x8*)(AlB + off) = L;
        }
    }
    __syncthreads();

    // ---- MFMA main: wave w = rows w*16..+16; sweep 16 n-iters of 64 cols ----
    const int w  = tid >> 6;
    const int l  = tid & 63;
    const int lr = l & 15, lk = l >> 4;
    const unsigned int aRowByte = (unsigned)((w*16 + lr) * 512);
    const unsigned int aSwz     = (unsigned)((lr & 7) << 4);

    float pd[4] = {0.f,0.f,0.f,0.f};
    float pr[4] = {0.f,0.f,0.f,0.f};

    #pragma unroll 1
    for (int n = 0; n < 16; ++n) {
        const _Float16* __restrict__ bp_h = WTh + (size_t)(n * 64) * SD;
        const _Float16* __restrict__ bp_l = WTl + (size_t)(n * 64) * SD;
        f32x4 acc[4];
        #pragma unroll
        for (int ni = 0; ni < 4; ++ni) acc[ni] = (f32x4){0.f,0.f,0.f,0.f};

        #pragma unroll 1
        for (int k = 0; k < 8; ++k) {
            f16x8 bh[4], bl[4];
            #pragma unroll
            for (int ni = 0; ni < 4; ++ni) {
                const size_t o = (size_t)(ni*16 + lr) * SD + k*32 + lk*8;
                bh[ni] = *(const f16x8*)(bp_h + o);
                bl[ni] = *(const f16x8*)(bp_l + o);
            }
            const unsigned int off = (aRowByte + (unsigned)(lk*16 + k*64)) ^ aSwz;
            const f16x8 ah = *(const f16x8*)(AhB + off);
            const f16x8 al = *(const f16x8*)(AlB + off);
            #pragma unroll
            for (int ni = 0; ni < 4; ++ni) {
                acc[ni] = __builtin_amdgcn_mfma_f32_16x16x32_f16(al, bh[ni], acc[ni], 0, 0, 0);
                acc[ni] = __builtin_amdgcn_mfma_f32_16x16x32_f16(ah, bl[ni], acc[ni], 0, 0, 0);
                acc[ni] = __builtin_amdgcn_mfma_f32_16x16x32_f16(ah, bh[ni], acc[ni], 0, 0, 0);
            }
        }
        // epilogue: bias + exact GELU + dot(w2) -> per-row partials
        const bool  isD = (n < 8);
        const float* __restrict__ B1 = isD ? db1 : rb1;
        const float* __restrict__ W2 = isD ? dw2 : rw2;
        #pragma unroll
        for (int ni = 0; ni < 4; ++ni) {
            const int col = (n & 7)*64 + ni*16 + lr;    // 0..511 within phase
            const float b1v = B1[col];
            const float w2v = W2[col];
            #pragma unroll
            for (int rg = 0; rg < 4; ++rg) {
                const float h = acc[ni][rg] + b1v;
                const float g = 0.5f * h * (1.0f + erff(h * 0.70710678118654752f));
                if (isD) pd[rg] = fmaf(g, w2v, pd[rg]);
                else     pr[rg] = fmaf(g, w2v, pr[rg]);
            }
        }
    }

    // ---- reduce across the 16 'lr' lanes (wave-local), write logits ---------
    #pragma unroll
    for (int m = 1; m <= 8; m <<= 1) {
        #pragma unroll
        for (int i = 0; i < 4; ++i) {
            pd[i] += __shfl_xor(pd[i], m);
            pr[i] += __shfl_xor(pr[i], m);
        }
    }
    if (lr == 0) {
        const float b2 = db2[0], r2 = rb2[0];
        #pragma unroll
        for (int rg = 0; rg < 4; ++rg) {
            const int row = w*16 + lk*4 + rg;
            const float D = pd[rg] + b2;
            const float R = pr[rg] + r2;
            const float sp = fmaxf(R, 0.f) + log1pf(expf(-fabsf(R)));
            float s = D - sp;
            s = fminf(CLIPV, fmaxf(-CLIPV, s));
            logits[row0 + (size_t)row] = s;
        }
    }
}

// ---------------------------------------------------------------------------
// K2: per-batch masked softmax over S + stable top-3 (validated R1/R2).
// ---------------------------------------------------------------------------
__global__ __launch_bounds__(256) void k_softmax_topk(
    const float* __restrict__ logits, const int* __restrict__ mask,
    float* __restrict__ weights, float* __restrict__ ti, float* __restrict__ tw,
    float* __restrict__ flags)
{
    const int b = blockIdx.x, tid = threadIdx.x;
    const float* lg = logits + (size_t)b * SS;
    const int*   mk = mask   + (size_t)b * SS;
    float*       wt = weights + (size_t)b * SS;
    __shared__ float rv[4];
    __shared__ int   ri[4];
    __shared__ int   sCh[3];

    float mx = -INFINITY;
    for (int s = tid; s < SS; s += 256) if (mk[s]) mx = fmaxf(mx, lg[s]);
    #pragma unroll
    for (int off = 32; off; off >>= 1) mx = fmaxf(mx, __shfl_xor(mx, off));
    if ((tid & 63) == 0) rv[tid >> 6] = mx;
    __syncthreads();
    mx = fmaxf(fmaxf(rv[0], rv[1]), fmaxf(rv[2], rv[3]));
    __syncthreads();

    float sm = 0.f;
    for (int s = tid; s < SS; s += 256) if (mk[s]) sm += expf(lg[s] - mx);
    #pragma unroll
    for (int off = 32; off; off >>= 1) sm += __shfl_xor(sm, off);
    if ((tid & 63) == 0) rv[tid >> 6] = sm;
    __syncthreads();
    const float Z = rv[0] + rv[1] + rv[2] + rv[3];
    __syncthreads();
    const bool  any = (Z > 0.f) && (mx > -INFINITY);
    const float inv = any ? 1.0f / Z : 0.f;

    for (int s = tid; s < SS; s += 256) {
        const float w = (mk[s] && any) ? expf(lg[s] - mx) * inv : 0.f;
        wt[s] = w;
    }
    if (tid == 0) flags[b] = any ? 1.f : 0.f;
    __syncthreads();

    for (int t = 0; t < 3; ++t) {
        float bv = -1.f; int bi = 0;
        for (int s = tid; s < SS; s += 256) {
            bool ex = false;
            for (int u = 0; u < t; ++u) ex = ex || (s == sCh[u]);
            if (ex) continue;
            const float w = wt[s];
            if (w > bv || (w == bv && s < bi)) { bv = w; bi = s; }
        }
        #pragma unroll
        for (int off = 32; off; off >>= 1) {
            const float ov = __shfl_xor(bv, off);
            const int   oi = __shfl_xor(bi, off);
            if (ov > bv || (ov == bv && oi < bi)) { bv = ov; bi = oi; }
        }
        if ((tid & 63) == 0) { rv[tid >> 6] = bv; ri[tid >> 6] = bi; }
        __syncthreads();
        if (tid == 0) {
            for (int w2 = 1; w2 < 4; ++w2)
                if (rv[w2] > rv[0] || (rv[w2] == rv[0] && ri[w2] < ri[0])) { rv[0] = rv[w2]; ri[0] = ri[w2]; }
            sCh[t] = ri[0];
            ti[b*3 + t] = (float)ri[0];
            tw[b*3 + t] = rv[0];
        }
        __syncthreads();
    }
}

// ---------------------------------------------------------------------------
// K3: partial weighted sums over S-chunks (validated R1/R2).
// ---------------------------------------------------------------------------
__global__ __launch_bounds__(256) void k_wsum(
    const float* __restrict__ x, const float* __restrict__ weights,
    const float* __restrict__ murstd,
    const float* __restrict__ gamma, const float* __restrict__ beta,
    float* __restrict__ partials)
{
    const int c = blockIdx.x;
    const int b = blockIdx.y;
    const int d = threadIdx.x;
    const float gg = gamma[d], bb = beta[d];
    float acc = 0.f;
    const size_t base = (size_t)b * SS + (size_t)c * 128;
    for (int s = 0; s < 128; ++s) {
        const size_t row = base + s;
        const float w = weights[row];
        if (w != 0.f) {
            const float mu = murstd[2*row], rs = murstd[2*row+1];
            const float xv = x[row * SD + d];
            acc = fmaf(w, (xv - mu) * rs * gg + bb, acc);
        }
    }
    partials[((size_t)b * 64 + c) * SD + d] = acc;
}

// ---------------------------------------------------------------------------
// K4: reduce partials, rep[b] = svec @ vw + vb * anyMask (validated R1/R2).
// ---------------------------------------------------------------------------
__global__ __launch_bounds__(256) void k_final(
    const float* __restrict__ partials, const float* __restrict__ flags,
    const float* __restrict__ vw, const float* __restrict__ vb,
    float* __restrict__ rep)
{
    const int b = blockIdx.x;
    const int t = threadIdx.x;
    __shared__ float sv[SD];
    float a = 0.f;
    for (int c = 0; c < 64; ++c) a += partials[((size_t)b * 64 + c) * SD + t];
    sv[t] = a;
    __syncthreads();
    const float f = flags[b];
    float r = vb[t] * f;
    for (int dd = 0; dd < SD; ++dd) r = fmaf(sv[dd], vw[(size_t)dd * 256 + t], r);
    rep[(size_t)b * 256 + t] = r;
}

// ---------------------------------------------------------------------------
extern "C" void kernel_launch(void* const* d_in, const int* in_sizes, int n_in,
                              void* d_out, int out_size, void* d_ws, size_t ws_size,
                              hipStream_t stream)
{
    const float* x     = (const float*)d_in[0];
    const int*   mask  = (const int*)  d_in[1];
    const float* gamma = (const float*)d_in[2];
    const float* beta  = (const float*)d_in[3];
    const float* dw1   = (const float*)d_in[4];
    const float* db1   = (const float*)d_in[5];
    const float* dw2   = (const float*)d_in[6];
    const float* db2   = (const float*)d_in[7];
    const float* rw1   = (const float*)d_in[8];
    const float* rb1   = (const float*)d_in[9];
    const float* rw2   = (const float*)d_in[10];
    const float* rb2   = (const float*)d_in[11];
    const float* vw    = (const float*)d_in[12];
    const float* vb    = (const float*)d_in[13];

    float* out     = (float*)d_out;
    float* rep     = out;                       // 32*256
    float* weights = out + 8192;                // 32*8192
    float* ti      = out + 8192 + 262144;       // 32*3
    float* tw      = ti + 96;                   // 32*3
    float* logits  = tw + 96;                   // 32*8192

    float* ws       = (float*)d_ws;
    float* murstd   = ws;                       // 524288 floats (2 MB)
    float* partials = ws + 524288;              // 524288 floats (2 MB)
    float* flags    = ws + 1048576;             // 32 floats (+pad)
    _Float16* WTh   = (_Float16*)(ws + 1048608);          // 512 KB
    _Float16* WTl   = WTh + 262144;                        // 512 KB

    hipLaunchKernelGGL(k_prepw, dim3(1024), dim3(256), 0, stream,
                       dw1, rw1, WTh, WTl);
    hipLaunchKernelGGL(k_logits, dim3(4096), dim3(256), 0, stream,
                       x, gamma, beta, WTh, WTl,
                       db1, dw2, db2, rb1, rw2, rb2,
                       logits, murstd);
    hipLaunchKernelGGL(k_softmax_topk, dim3(32), dim3(256), 0, stream,
                       logits, mask, weights, ti, tw, flags);
    hipLaunchKernelGGL(k_wsum, dim3(64, 32), dim3(256), 0, stream,
                       x, weights, murstd, gamma, beta, partials);
    hipLaunchKernelGGL(k_final, dim3(32), dim3(256), 0, stream,
                       partials, flags, vw, vb, rep);
}